// Round 4
// baseline (273.396 us; speedup 1.0000x reference)
//
#include <hip/hip_runtime.h>
#include <math.h>

// Problem constants (x: [4, 64, 384, 384] fp32)
#define QLS_T   256            // B*C = 4*64, sequential scan axis
#define QLS_HW  (384 * 384)    // independent spatial locations
#define QLS_HW2 (QLS_HW / 2)   // float2 granularity
#define QLS_HW4 (QLS_HW / 4)   // float4 granularity (36864)

// Quantizer constants from the reference
#define Q_SCALE      16.0f
#define INV_Q_SCALE  (1.0f / 16.0f)
#define QMAXF        7.9375f
#define QMINF        (-8.0f)
#define LUT_IN_SCALE 4096.0f
#define LUT_IN_MAX   32767.0f
#define INV_LUT_OUT  (1.0f / 65536.0f)

// log1p(exp(-d)) = log2(1 + 2^(-d*log2e)) * ln2, on raw v_exp_f32/v_log_f32.
#define NEG_LOG2E_DIV (-1.4426950408889634f / 4096.0f)
#define LN2_X_65536   45426.09375f

#define PF 16   // prefetch depth (float2 steps): 16 x 512B x ~4.5 waves/CU = 36KB/CU in flight

// Native clang vector types: __builtin_nontemporal_store accepts these,
// but NOT HIP's struct-based float4 (R3 compile failure).
typedef float f32x4 __attribute__((ext_vector_type(4)));
typedef float f32x2 __attribute__((ext_vector_type(2)));

__device__ __forceinline__ float qls_step(float s, float v) {
    float diff = fabsf(s - v);
    float d_int = fminf(floorf(diff * LUT_IN_SCALE), LUT_IN_MAX);
    float e  = __builtin_amdgcn_exp2f(d_int * NEG_LOG2E_DIV);
    float lu = rintf(__builtin_amdgcn_logf(1.0f + e) * LN2_X_65536) * INV_LUT_OUT;
    s = fmaxf(s, v) + lu;
    return fminf(fmaxf(s, QMINF), QMAXF);
}

// ---------------- Kernel 1: scan pass ----------------
// 2 locations/thread, float2 loads -> 512B per wave-request (R3 theory:
// 256B scattered requests cap HBM near ~3TB/s; wider requests + half the
// request count should lift toward the float4-measured 6.3TB/s ceiling).
// 1152 single-wave blocks = 4.5 waves/CU. Scan order per location is
// bit-identical to the reference.
__global__ __launch_bounds__(64) void qls_scan_kernel(
    const float* __restrict__ x, float* __restrict__ sbuf) {
    const int i2 = blockIdx.x * 64 + threadIdx.x;   // float2 index in [0, HW/2)
    const f32x2* xp = reinterpret_cast<const f32x2*>(x) + i2;

    f32x2 buf[PF];
    #pragma unroll
    for (int p = 0; p < PF; ++p) buf[p] = xp[p * QLS_HW2];

    float sa = QMINF, sb = QMINF;
    for (int t0 = 0; t0 < QLS_T - PF; t0 += PF) {
        f32x2 nxt[PF];
        #pragma unroll
        for (int p = 0; p < PF; ++p) nxt[p] = xp[(t0 + PF + p) * QLS_HW2];
        #pragma unroll
        for (int p = 0; p < PF; ++p) {
            sa = qls_step(sa, buf[p].x);
            sb = qls_step(sb, buf[p].y);
        }
        #pragma unroll
        for (int p = 0; p < PF; ++p) buf[p] = nxt[p];
    }
    #pragma unroll
    for (int p = 0; p < PF; ++p) {
        sa = qls_step(sa, buf[p].x);
        sb = qls_step(sb, buf[p].y);
    }

    f32x2 sv; sv.x = sa; sv.y = sb;
    reinterpret_cast<f32x2*>(sbuf)[i2] = sv;
}

// ---------------- Kernel 2: output pass ----------------
// Fully parallel: one thread per (4 t-planes x 4 locations). float4 reads of
// x hit L3 (memory-side Infinity Cache stays warm across the kernel
// boundary); float4 NT writes to out. 9216 blocks x 256 threads covers
// exactly 64 t-groups x 36864 loc4 work items (R5 fix: previous grid had a
// stray x4 -> threads with tb up to 1020 -> OOB fault).
__global__ __launch_bounds__(256) void qls_out_kernel(
    const float* __restrict__ x, const float* __restrict__ sbuf,
    float* __restrict__ out) {
    const int idx  = blockIdx.x * 256 + threadIdx.x;  // [0, 2359296)
    const int loc4 = idx % QLS_HW4;
    const int tb   = (idx / QLS_HW4) * 4;

    const f32x4 s4 = reinterpret_cast<const f32x4*>(sbuf)[loc4];

    #pragma unroll
    for (int k = 0; k < 4; ++k) {
        const int t = tb + k;
        const f32x4 v = reinterpret_cast<const f32x4*>(x + (size_t)t * QLS_HW)[loc4];
        f32x4 q;
        q.x = fminf(fmaxf(rintf((v.x - s4.x) * Q_SCALE), -128.0f), 127.0f) * INV_Q_SCALE;
        q.y = fminf(fmaxf(rintf((v.y - s4.y) * Q_SCALE), -128.0f), 127.0f) * INV_Q_SCALE;
        q.z = fminf(fmaxf(rintf((v.z - s4.z) * Q_SCALE), -128.0f), 127.0f) * INV_Q_SCALE;
        q.w = fminf(fmaxf(rintf((v.w - s4.w) * Q_SCALE), -128.0f), 127.0f) * INV_Q_SCALE;
        __builtin_nontemporal_store(q, reinterpret_cast<f32x4*>(out + (size_t)t * QLS_HW) + loc4);
    }
}

// ---------------- Fallback: R2 fused kernel (if workspace too small) ----------------
__global__ __launch_bounds__(64) void qls_fused_kernel(
    const float* __restrict__ x, float* __restrict__ out) {
    const int i = blockIdx.x * 64 + threadIdx.x;
    const float* xp = x + i;

    float buf[PF];
    #pragma unroll
    for (int p = 0; p < PF; ++p) buf[p] = xp[p * QLS_HW];

    float s = QMINF;
    for (int t0 = 0; t0 < QLS_T - PF; t0 += PF) {
        float nxt[PF];
        #pragma unroll
        for (int p = 0; p < PF; ++p) nxt[p] = xp[(t0 + PF + p) * QLS_HW];
        #pragma unroll
        for (int p = 0; p < PF; ++p) s = qls_step(s, buf[p]);
        #pragma unroll
        for (int p = 0; p < PF; ++p) buf[p] = nxt[p];
    }
    #pragma unroll
    for (int p = 0; p < PF; ++p) s = qls_step(s, buf[p]);

    float* op = out + i;
    #pragma unroll 16
    for (int t = 0; t < QLS_T; ++t) {
        float v = xp[t * QLS_HW];
        float q = fminf(fmaxf(rintf((v - s) * Q_SCALE), -128.0f), 127.0f);
        __builtin_nontemporal_store(q * INV_Q_SCALE, op + t * QLS_HW);
    }
}

extern "C" void kernel_launch(void* const* d_in, const int* in_sizes, int n_in,
                              void* d_out, int out_size, void* d_ws, size_t ws_size,
                              hipStream_t stream) {
    const float* x = (const float*)d_in[0];
    float* out = (float*)d_out;
    const size_t s_bytes = (size_t)QLS_HW * sizeof(float);  // 576 KB

    if (d_ws != nullptr && ws_size >= s_bytes) {
        float* sbuf = (float*)d_ws;
        qls_scan_kernel<<<QLS_HW2 / 64, 64, 0, stream>>>(x, sbuf);               // 1152 blocks
        qls_out_kernel<<<(QLS_T / 4) * (QLS_HW4 / 256), 256, 0, stream>>>(x, sbuf, out); // 9216 blocks
    } else {
        qls_fused_kernel<<<QLS_HW / 64, 64, 0, stream>>>(x, out);                // 2304 blocks
    }
}

// Round 5
// 268.391 us; speedup vs baseline: 1.0186x; 1.0186x over previous
//
#include <hip/hip_runtime.h>
#include <math.h>

// Problem constants (x: [4, 64, 384, 384] fp32)
#define QLS_T   256            // B*C = 4*64, sequential scan axis
#define QLS_HW  (384 * 384)    // independent spatial locations
#define CHUNK   8              // parallel t-chunks per location (re-associated scan)
#define TPC     (QLS_T / CHUNK) // 32 planes per chunk

// Quantizer constants from the reference
#define Q_SCALE      16.0f
#define INV_Q_SCALE  (1.0f / 16.0f)
#define QMAXF        7.9375f
#define QMINF        (-8.0f)
#define LUT_IN_SCALE 4096.0f
#define LUT_IN_MAX   32767.0f
#define INV_LUT_OUT  (1.0f / 65536.0f)

// log1p(exp(-d)) = log2(1 + 2^(-d*log2e)) * ln2, on raw v_exp_f32/v_log_f32.
#define NEG_LOG2E_DIV (-1.4426950408889634f / 4096.0f)
#define LN2_X_65536   45426.09375f

__device__ __forceinline__ float qls_step(float s, float v) {
    float diff = fabsf(s - v);
    float d_int = fminf(floorf(diff * LUT_IN_SCALE), LUT_IN_MAX);
    float e  = __builtin_amdgcn_exp2f(d_int * NEG_LOG2E_DIV);
    float lu = rintf(__builtin_amdgcn_logf(1.0f + e) * LN2_X_65536) * INV_LUT_OUT;
    s = fmaxf(s, v) + lu;
    return fminf(fmaxf(s, QMINF), QMAXF);
}

// Chunked-scan fused kernel (R7).
// R3/R6 post-mortem: MLP depth (PF=16) and request width (float2) both
// changed nothing -> the ~3 TB/s cap tracks the scan's structure: 4.5-9
// waves/CU, 256-step serial chain, and a second trip over x. logaddexp is
// associative, so re-associate: 8 chunks of 32 planes scanned in parallel
// (8 waves/block, one chunk per wave), partials merged with the SAME
// quantized op via LDS. Re-association error (7 phantom e^-8 init masses
// + ~1/65536 roundings) shifts s by ~1e-5 << 1/32 -> output flips stay at
// +-1 grid step, absmax stays 0.0625.
//
// Each thread keeps its chunk's 32 x-values in VGPRs through the merge and
// reuses them for the output pass: x is read from HBM exactly once, out is
// written once (NT), no L3 re-read. 2304 blocks x 512 threads = 72 waves/CU
// queued, 16 resident at <=128 VGPR -> read stream finally has CU-level
// parallelism (vs 4.5 waves/CU in R6).
__global__ __launch_bounds__(512, 4) void qls_chunked_kernel(
    const float* __restrict__ x, float* __restrict__ out) {
    const int lane  = threadIdx.x & 63;          // location lane within block
    const int chunk = threadIdx.x >> 6;          // 0..7, one t-chunk per wave
    const int loc   = blockIdx.x * 64 + lane;    // spatial index
    const size_t base = (size_t)loc + (size_t)chunk * TPC * QLS_HW;
    const float* xp = x + base;

    // Load this chunk's 32 planes into registers (32 coalesced 256B
    // wave-requests issued back-to-back; compiler waits per-use).
    float v[TPC];
    #pragma unroll
    for (int k = 0; k < TPC; ++k) v[k] = xp[(size_t)k * QLS_HW];

    // Sequential scan within the chunk (32-step chain, order-preserving).
    float s = QMINF;
    #pragma unroll
    for (int k = 0; k < TPC; ++k) s = qls_step(s, v[k]);

    // Merge the 8 chunk partials in t-order with the same quantized op.
    __shared__ float part[CHUNK][64];
    part[chunk][lane] = s;
    __syncthreads();

    float tot = part[0][lane];
    #pragma unroll
    for (int c = 1; c < CHUNK; ++c) tot = qls_step(tot, part[c][lane]);

    // Output pass straight from registers: quantize to 1/16 grid, NT store.
    float* op = out + base;
    #pragma unroll
    for (int k = 0; k < TPC; ++k) {
        float q = fminf(fmaxf(rintf((v[k] - tot) * Q_SCALE), -128.0f), 127.0f);
        __builtin_nontemporal_store(q * INV_Q_SCALE, op + (size_t)k * QLS_HW);
    }
}

extern "C" void kernel_launch(void* const* d_in, const int* in_sizes, int n_in,
                              void* d_out, int out_size, void* d_ws, size_t ws_size,
                              hipStream_t stream) {
    const float* x = (const float*)d_in[0];
    float* out = (float*)d_out;
    const int blocks = QLS_HW / 64;  // 2304 blocks x 512 threads
    qls_chunked_kernel<<<blocks, 512, 0, stream>>>(x, out);
}